// Round 2
// baseline (577.899 us; speedup 1.0000x reference)
//
#include <hip/hip_runtime.h>
#include <stdint.h>

#define N_ROWS  8192   // B*S = 4*2048
#define DIM     256
#define K_CODES 8192
#define SPLITK  8
#define KS      (K_CODES / SPLITK)   // 1024 codes per split
#define TM      128                  // rows per block
#define TK      128                  // codes per k-tile
#define BD      16                   // D-chunk staged in LDS
#define LDS_STRIDE 132               // padded (128+4) to break bank conflicts

typedef unsigned long long u64;

__device__ __forceinline__ u64 u64min(u64 a, u64 b) { return a < b ? a : b; }

// ---------------------------------------------------------------- kernel A
// xnorm[n] = sum_d z_e[n][d]^2 ; cnorm[k] = sum_d cb[k][d]^2
// one wave per row, pairwise tree reduction (float4 partials + 6-level xor).
// grid: (N_ROWS+K_CODES) waves total, 4 waves per 256-thread block.
__global__ __launch_bounds__(256) void vq_norms(const float* __restrict__ z_e,
                                                const float* __restrict__ cb,
                                                float* __restrict__ xnorm,
                                                float* __restrict__ cnorm) {
    int wid  = (blockIdx.x * 256 + threadIdx.x) >> 6;  // global wave id
    int lane = threadIdx.x & 63;
    const float* src;
    float* dst;
    if (wid < N_ROWS) { src = z_e + (size_t)wid * DIM;            dst = xnorm + wid; }
    else              { int k = wid - N_ROWS;
                        src = cb  + (size_t)k   * DIM;            dst = cnorm + k;   }
    float4 v = *(const float4*)(src + lane * 4);
    float t0 = v.x * v.x, t1 = v.y * v.y, t2 = v.z * v.z, t3 = v.w * v.w;
    float s = (t0 + t1) + (t2 + t3);
#pragma unroll
    for (int off = 1; off < 64; off <<= 1)
        s += __shfl_xor(s, off, 64);
    if (lane == 0) *dst = s;
}

// ---------------------------------------------------------------- kernel B
// Fused distance GEMM + argmin. Block: TM=128 rows x KS=1024 codes (split k).
// 256 threads as 16x16; each thread owns an 8x8 micro-tile (2x2 groups of 4x4).
// dist = fmaf(-2, dot, xnorm) + cnorm  -- matches reference rounding order.
// argmin carried as u64 key = (bits(dist)<<32)|code_idx  (dist>0 => monotone),
// so u64-min gives min-dist with lowest-index tie-break for free.
__global__ __launch_bounds__(256) void vq_argmin(const float* __restrict__ z_e,
                                                 const float* __restrict__ cb,
                                                 const float* __restrict__ xnorm,
                                                 const float* __restrict__ cnorm,
                                                 u64* __restrict__ pkey) {
    __shared__ float Xs[BD][LDS_STRIDE];
    __shared__ float Cs[BD][LDS_STRIDE];
    __shared__ u64   red[TM][17];            // [row][tx], padded

    const int tid   = threadIdx.x;
    const int tx    = tid & 15;
    const int ty    = tid >> 4;
    const int n0    = blockIdx.x * TM;
    const int split = blockIdx.y;
    const int k_begin = split * KS;

    float xn[8];
#pragma unroll
    for (int ig = 0; ig < 2; ig++)
#pragma unroll
        for (int i = 0; i < 4; i++)
            xn[ig * 4 + i] = xnorm[n0 + ig * 64 + ty * 4 + i];

    u64 best[8];
#pragma unroll
    for (int r = 0; r < 8; r++) best[r] = ~0ULL;

    for (int kt = 0; kt < KS; kt += TK) {
        const int k0 = k_begin + kt;
        float acc[8][8];
#pragma unroll
        for (int a = 0; a < 8; a++)
#pragma unroll
            for (int b = 0; b < 8; b++) acc[a][b] = 0.0f;

        for (int d0 = 0; d0 < DIM; d0 += BD) {
            __syncthreads();   // previous chunk's reads done before overwrite
            // stage X and C chunks: 128 rows x 16 cols each = 512 float4 / array
#pragma unroll
            for (int l = 0; l < 2; l++) {
                int f   = tid + l * 256;
                int row = f >> 2;
                int c4  = f & 3;
                float4 xv = *(const float4*)(z_e + (size_t)(n0 + row) * DIM + d0 + c4 * 4);
                float4 cv = *(const float4*)(cb  + (size_t)(k0 + row) * DIM + d0 + c4 * 4);
                Xs[c4 * 4 + 0][row] = xv.x; Xs[c4 * 4 + 1][row] = xv.y;
                Xs[c4 * 4 + 2][row] = xv.z; Xs[c4 * 4 + 3][row] = xv.w;
                Cs[c4 * 4 + 0][row] = cv.x; Cs[c4 * 4 + 1][row] = cv.y;
                Cs[c4 * 4 + 2][row] = cv.z; Cs[c4 * 4 + 3][row] = cv.w;
            }
            __syncthreads();
#pragma unroll
            for (int dk = 0; dk < BD; dk++) {
                float xa[8], cc[8];
                *(float4*)&xa[0] = *(const float4*)&Xs[dk][ty * 4];
                *(float4*)&xa[4] = *(const float4*)&Xs[dk][64 + ty * 4];
                *(float4*)&cc[0] = *(const float4*)&Cs[dk][tx * 4];
                *(float4*)&cc[4] = *(const float4*)&Cs[dk][64 + tx * 4];
#pragma unroll
                for (int a = 0; a < 8; a++)
#pragma unroll
                    for (int b = 0; b < 8; b++)
                        acc[a][b] = __builtin_fmaf(xa[a], cc[b], acc[a][b]);
            }
        }
        // epilogue: distances + argmin update for this 128-code tile
#pragma unroll
        for (int jg = 0; jg < 2; jg++)
#pragma unroll
            for (int j = 0; j < 4; j++) {
                int kk   = k0 + jg * 64 + tx * 4 + j;
                float cn = cnorm[kk];
#pragma unroll
                for (int r = 0; r < 8; r++) {
                    float m    = acc[r][jg * 4 + j];
                    float t1   = __builtin_fmaf(-2.0f, m, xn[r]); // == xn - fl(2m), exact
                    float dist = t1 + cn;
                    u64 key = ((u64)__float_as_uint(dist) << 32) | (unsigned)kk;
                    best[r] = u64min(best[r], key);
                }
            }
    }

    // block reduce across tx (16 threads share each row)
    __syncthreads();
#pragma unroll
    for (int ig = 0; ig < 2; ig++)
#pragma unroll
        for (int i = 0; i < 4; i++)
            red[ig * 64 + ty * 4 + i][tx] = best[ig * 4 + i];
    __syncthreads();
    if (tid < TM) {
        u64 b = red[tid][0];
#pragma unroll
        for (int t = 1; t < 16; t++) b = u64min(b, red[tid][t]);
        pkey[(size_t)(n0 + tid) * SPLITK + split] = b;
    }
}

// ---------------------------------------------------------------- kernel C
// Per row: combine split partials -> index; gather code row; z_q_st with the
// reference's double rounding x + (c - x); per-row squared-error sum.
__global__ __launch_bounds__(64) void vq_gather(const float* __restrict__ z_e,
                                                const float* __restrict__ cb,
                                                const u64* __restrict__ pkey,
                                                float* __restrict__ out_zq,
                                                float* __restrict__ out_idx,
                                                float* __restrict__ rowloss) {
    int n    = blockIdx.x;
    int lane = threadIdx.x;
    u64 b = pkey[(size_t)n * SPLITK];
#pragma unroll
    for (int s = 1; s < SPLITK; s++) b = u64min(b, pkey[(size_t)n * SPLITK + s]);
    int idx = (int)(unsigned)(b & 0xffffffffu);

    float4 x = *(const float4*)(z_e + (size_t)n * DIM + lane * 4);
    float4 c = *(const float4*)(cb + (size_t)idx * DIM + lane * 4);
    float4 st;
    st.x = x.x + (c.x - x.x); st.y = x.y + (c.y - x.y);
    st.z = x.z + (c.z - x.z); st.w = x.w + (c.w - x.w);
    *(float4*)(out_zq + (size_t)n * DIM + lane * 4) = st;

    float d0 = x.x - c.x, d1 = x.y - c.y, d2 = x.z - c.z, d3 = x.w - c.w;
    float s2 = (d0 * d0 + d1 * d1) + (d2 * d2 + d3 * d3);
#pragma unroll
    for (int off = 1; off < 64; off <<= 1)
        s2 += __shfl_xor(s2, off, 64);
    if (lane == 0) {
        rowloss[n] = s2;
        out_idx[n] = (float)idx;
    }
}

// ---------------------------------------------------------------- kernel D
__global__ __launch_bounds__(256) void vq_loss(const float* __restrict__ rowloss,
                                               float* __restrict__ out_loss) {
    __shared__ double sd[256];
    double s = 0.0;
    for (int i = threadIdx.x; i < N_ROWS; i += 256) s += (double)rowloss[i];
    sd[threadIdx.x] = s;
    __syncthreads();
    for (int off = 128; off; off >>= 1) {
        if (threadIdx.x < off) sd[threadIdx.x] += sd[threadIdx.x + off];
        __syncthreads();
    }
    if (threadIdx.x == 0) {
        double mean = sd[0] / (double)((size_t)N_ROWS * DIM);
        out_loss[0] = (float)(1.25 * mean);   // codebook + 0.25*commitment (same value)
    }
}

// ---------------------------------------------------------------- launch
extern "C" void kernel_launch(void* const* d_in, const int* in_sizes, int n_in,
                              void* d_out, int out_size, void* d_ws, size_t ws_size,
                              hipStream_t stream) {
    const float* z_e = (const float*)d_in[0];
    const float* cb  = (const float*)d_in[1];

    float* out   = (float*)d_out;
    float* zq    = out;                               // 8192*256
    float* oidx  = out + (size_t)N_ROWS * DIM;        // 8192
    float* oloss = oidx + N_ROWS;                     // 1

    // ws layout: cnorm[8192] | xnorm[8192] | pkey[8192*8 u64] | rowloss[8192]
    float* cnorm   = (float*)d_ws;
    float* xnorm   = cnorm + K_CODES;
    u64*   pkey    = (u64*)(xnorm + N_ROWS);
    float* rowloss = (float*)(pkey + (size_t)N_ROWS * SPLITK);

    // FIX(R1): grid was /(4*64) => only 256 of 16384 norms computed, cnorm
    // stayed 0xAA-poison => wrong argmin. 4 waves/block => /4.
    vq_norms <<<(N_ROWS + K_CODES) / 4, 256, 0, stream>>>(z_e, cb, xnorm, cnorm);
    vq_argmin<<<dim3(N_ROWS / TM, SPLITK), 256, 0, stream>>>(z_e, cb, xnorm, cnorm, pkey);
    vq_gather<<<N_ROWS, 64, 0, stream>>>(z_e, cb, pkey, zq, oidx, rowloss);
    vq_loss  <<<1, 256, 0, stream>>>(rowloss, oloss);
}

// Round 3
// 306.615 us; speedup vs baseline: 1.8848x; 1.8848x over previous
//
#include <hip/hip_runtime.h>
#include <stdint.h>

#define N_ROWS  8192   // B*S = 4*2048
#define DIM     256
#define K_CODES 8192
#define SPLITK  8
#define KS      1024          // codes per split
#define NT      128           // codes per N-tile
#define BK      64            // dims per LDS stage
#define XSTR    72            // LDS row stride in bf16 elems (64+8: keeps 16B align, breaks pow2)
#define LSLOTS  24            // per-row-split append slots in LDS
#define GSLOTS  8             // per-row-split survivor slots in ws
#define MARGIN  2.0e-4f       // >= bucket(3.05e-5@256) + 2*max bf16 dist error (~4e-5)

typedef unsigned long long u64;
typedef short s16x8 __attribute__((ext_vector_type(8)));   // 8 bf16 = 4 VGPR
typedef float f32x4 __attribute__((ext_vector_type(4)));

__device__ __forceinline__ u64 u64min(u64 a, u64 b) { return a < b ? a : b; }

// float -> bf16 bits, round-to-nearest-even (matches v_cvt_pk_bf16_f32; no NaN inputs)
__device__ __forceinline__ unsigned short f2bf(float f) {
    unsigned u = __float_as_uint(f);
    u += 0x7fffu + ((u >> 16) & 1u);
    return (unsigned short)(u >> 16);
}

// ---------------------------------------------------------------- kernel A
// xnorm[n] = ||z_e[n]||^2 ; cnorm[k] = ||cb[k]||^2 (one wave per row)
__global__ __launch_bounds__(256) void vq_norms(const float* __restrict__ z_e,
                                                const float* __restrict__ cb,
                                                float* __restrict__ xnorm,
                                                float* __restrict__ cnorm) {
    int wid  = (blockIdx.x * 256 + threadIdx.x) >> 6;
    int lane = threadIdx.x & 63;
    const float* src;
    float* dst;
    if (wid < N_ROWS) { src = z_e + (size_t)wid * DIM; dst = xnorm + wid; }
    else              { int k = wid - N_ROWS;
                        src = cb  + (size_t)k   * DIM; dst = cnorm + k; }
    float4 v = *(const float4*)(src + lane * 4);
    float s = (v.x * v.x + v.y * v.y) + (v.z * v.z + v.w * v.w);
#pragma unroll
    for (int off = 1; off < 64; off <<= 1)
        s += __shfl_xor(s, off, 64);
    if (lane == 0) *dst = s;
}

// ---------------------------------------------------------------- kernel B
// bf16 MFMA distance GEMM + per-row running min + margin-candidate emission.
// Block: 128 rows x 1024 codes (one split), 4 waves in 2x2 (wm row-half,
// wn col-half). Wave tile 64x64 = 4x4 MFMA 16x16x32 tiles.
// C/D layout (verified): col=lane&15, row=(lane>>4)*4+reg.
// A frag: A[m=lane&15][k=quad*8+j]; B frag from B^T rows, mirrored.
__global__ __launch_bounds__(256, 2) void vq_mfma(const float* __restrict__ z_e,
                                                  const float* __restrict__ cb,
                                                  const float* __restrict__ xnorm,
                                                  const float* __restrict__ cnorm,
                                                  int* __restrict__ cand_cnt,
                                                  int* __restrict__ cand_idx) {
    __shared__ short    Xs[128 * XSTR];
    __shared__ short    Cs[128 * XSTR];
    __shared__ unsigned smin[128];       // per-row tile-min (shared across waves)
    __shared__ float    gmin[128];       // per-row final split min
    __shared__ float    lcd[128 * LSLOTS];
    __shared__ int      lci[128 * LSLOTS];
    __shared__ int      lcnt[128];

    const int tid   = threadIdx.x;
    const int lane  = tid & 63;
    const int wave  = tid >> 6;
    const int wm    = wave & 1;
    const int wn    = wave >> 1;
    const int quad  = lane >> 4;
    const int l16   = lane & 15;
    const int split = blockIdx.x;
    const int n0    = blockIdx.y * 128;

    if (tid < 128) lcnt[tid] = 0;

    float xnr[16];
#pragma unroll
    for (int i = 0; i < 4; i++)
#pragma unroll
        for (int r = 0; r < 4; r++)
            xnr[i * 4 + r] = xnorm[n0 + wm * 64 + i * 16 + quad * 4 + r];

    float runmin[16];
#pragma unroll
    for (int t = 0; t < 16; t++) runmin[t] = 3.0e38f;

    const int srow = tid >> 1;  // staging: 2 threads per row
    const int sseg = tid & 1;   // 32-float half

    for (int nt = 0; nt < KS / NT; nt++) {
        const int kbase = split * KS + nt * NT;
        if (tid < 128) smin[tid] = 0xFFFFFFFFu;

        f32x4 acc[4][4];
#pragma unroll
        for (int i = 0; i < 4; i++)
#pragma unroll
            for (int j = 0; j < 4; j++)
#pragma unroll
                for (int e = 0; e < 4; e++) acc[i][j][e] = 0.0f;

        for (int kc = 0; kc < DIM / BK; kc++) {
            __syncthreads();  // prev reads of Xs/Cs + smin reset ordering
            {
                const float4* px = (const float4*)(z_e + (size_t)(n0 + srow) * DIM + kc * BK + sseg * 32);
                const float4* pc = (const float4*)(cb  + (size_t)(kbase + srow) * DIM + kc * BK + sseg * 32);
                short* dx = &Xs[srow * XSTR + sseg * 32];
                short* dc = &Cs[srow * XSTR + sseg * 32];
#pragma unroll
                for (int g = 0; g < 4; g++) {
                    float4 a = px[2 * g], b = px[2 * g + 1];
                    union { unsigned short h[8]; s16x8 v; } u;
                    u.h[0] = f2bf(a.x); u.h[1] = f2bf(a.y); u.h[2] = f2bf(a.z); u.h[3] = f2bf(a.w);
                    u.h[4] = f2bf(b.x); u.h[5] = f2bf(b.y); u.h[6] = f2bf(b.z); u.h[7] = f2bf(b.w);
                    *(s16x8*)(dx + g * 8) = u.v;
                    a = pc[2 * g]; b = pc[2 * g + 1];
                    u.h[0] = f2bf(a.x); u.h[1] = f2bf(a.y); u.h[2] = f2bf(a.z); u.h[3] = f2bf(a.w);
                    u.h[4] = f2bf(b.x); u.h[5] = f2bf(b.y); u.h[6] = f2bf(b.z); u.h[7] = f2bf(b.w);
                    *(s16x8*)(dc + g * 8) = u.v;
                }
            }
            __syncthreads();
#pragma unroll
            for (int ks = 0; ks < 2; ks++) {
                s16x8 af[4], bfr[4];
#pragma unroll
                for (int i = 0; i < 4; i++)
                    af[i] = *(const s16x8*)&Xs[(wm * 64 + i * 16 + l16) * XSTR + ks * 32 + quad * 8];
#pragma unroll
                for (int j = 0; j < 4; j++)
                    bfr[j] = *(const s16x8*)&Cs[(wn * 64 + j * 16 + l16) * XSTR + ks * 32 + quad * 8];
#pragma unroll
                for (int i = 0; i < 4; i++)
#pragma unroll
                    for (int j = 0; j < 4; j++)
                        acc[i][j] = __builtin_amdgcn_mfma_f32_16x16x32_bf16(af[i], bfr[j], acc[i][j], 0, 0, 0);
            }
        }

        // ---- epilogue: dist in place, shared per-row tile min, margin appends
        float cnv[4];
#pragma unroll
        for (int j = 0; j < 4; j++) cnv[j] = cnorm[kbase + wn * 64 + j * 16 + l16];
#pragma unroll
        for (int i = 0; i < 4; i++)
#pragma unroll
            for (int j = 0; j < 4; j++)
#pragma unroll
                for (int r = 0; r < 4; r++)
                    acc[i][j][r] = __builtin_fmaf(-2.0f, acc[i][j][r], xnr[i * 4 + r]) + cnv[j];

#pragma unroll
        for (int i = 0; i < 4; i++)
#pragma unroll
            for (int r = 0; r < 4; r++) {
                float m = fminf(fminf(acc[i][0][r], acc[i][1][r]),
                                fminf(acc[i][2][r], acc[i][3][r]));
                m = fminf(m, __shfl_xor(m, 1, 64));
                m = fminf(m, __shfl_xor(m, 2, 64));
                m = fminf(m, __shfl_xor(m, 4, 64));
                m = fminf(m, __shfl_xor(m, 8, 64));
                if (l16 == 0)
                    atomicMin(&smin[wm * 64 + i * 16 + quad * 4 + r], __float_as_uint(m));
            }
        __syncthreads();
#pragma unroll
        for (int i = 0; i < 4; i++)
#pragma unroll
            for (int r = 0; r < 4; r++) {
                int rl = wm * 64 + i * 16 + quad * 4 + r;
                float sm = __uint_as_float(smin[rl]);
                runmin[i * 4 + r] = fminf(runmin[i * 4 + r], sm);
                float thr = runmin[i * 4 + r] + MARGIN;
#pragma unroll
                for (int j = 0; j < 4; j++) {
                    float d = acc[i][j][r];
                    if (d <= thr) {
                        int pos = atomicAdd(&lcnt[rl], 1);
                        if (pos < LSLOTS) {
                            lcd[rl * LSLOTS + pos] = d;
                            lci[rl * LSLOTS + pos] = kbase + wn * 64 + j * 16 + l16;
                        }
                    }
                }
            }
        __syncthreads();  // appends/smin reads done before next tile's reset
    }

    // final per-row split min -> gmin (wn==0 waves cover all 128 rows uniquely)
    if (l16 == 0 && wn == 0) {
#pragma unroll
        for (int i = 0; i < 4; i++)
#pragma unroll
            for (int r = 0; r < 4; r++)
                gmin[wm * 64 + i * 16 + quad * 4 + r] = runmin[i * 4 + r];
    }
    __syncthreads();

    // filter appends vs final min; write survivors (winner guaranteed present)
    if (tid < 128) {
        int n = n0 + tid;
        int cnt = lcnt[tid]; if (cnt > LSLOTS) cnt = LSLOTS;
        float thrf = gmin[tid] + MARGIN;
        int base = (n * SPLITK + split) * GSLOTS;
        int w = 0;
        for (int s = 0; s < cnt && w < GSLOTS; s++) {
            if (lcd[tid * LSLOTS + s] <= thrf) {
                cand_idx[base + w] = lci[tid * LSLOTS + s];
                w++;
            }
        }
        cand_cnt[n * SPLITK + split] = w;
    }
}

// ---------------------------------------------------------------- kernel C
// Exact re-check of candidates (bit-identical association to the R2-passing
// kernel: sequential fmaf d=0..255, fmaf(-2,m,xn)+cn), lexicographic
// (dist,idx) min; then gather + z_q_st + rowloss. One wave per row.
__global__ __launch_bounds__(256) void vq_finalize(const float* __restrict__ z_e,
                                                   const float* __restrict__ cb,
                                                   const float* __restrict__ xnorm,
                                                   const float* __restrict__ cnorm,
                                                   const int* __restrict__ cand_cnt,
                                                   const int* __restrict__ cand_idx,
                                                   float* __restrict__ out_zq,
                                                   float* __restrict__ out_idx,
                                                   float* __restrict__ rowloss) {
    const int n    = blockIdx.x * 4 + (threadIdx.x >> 6);
    const int lane = threadIdx.x & 63;

    int myidx = -1;
    int t = 0;
#pragma unroll
    for (int s = 0; s < SPLITK; s++) {
        int c = cand_cnt[n * SPLITK + s];
        if (lane >= t && lane < t + c)
            myidx = cand_idx[(n * SPLITK + s) * GSLOTS + (lane - t)];
        t += c;
    }

    u64 key = ~0ULL;
    if (myidx >= 0) {
        const float* xr = z_e + (size_t)n * DIM;
        const float* cr = cb + (size_t)myidx * DIM;
        float acc = 0.0f;
#pragma unroll 8
        for (int d = 0; d < DIM; d++)
            acc = __builtin_fmaf(xr[d], cr[d], acc);
        float dist = __builtin_fmaf(-2.0f, acc, xnorm[n]) + cnorm[myidx];
        key = ((u64)__float_as_uint(dist) << 32) | (unsigned)myidx;
    }
#pragma unroll
    for (int off = 1; off < 64; off <<= 1)
        key = u64min(key, __shfl_xor(key, off, 64));

    int idx = (int)(unsigned)(key & 0xffffffffu);
    if (key == ~0ULL) idx = 0;  // unreachable safety

    float4 x = *(const float4*)(z_e + (size_t)n * DIM + lane * 4);
    float4 c = *(const float4*)(cb + (size_t)idx * DIM + lane * 4);
    float4 st;
    st.x = x.x + (c.x - x.x); st.y = x.y + (c.y - x.y);
    st.z = x.z + (c.z - x.z); st.w = x.w + (c.w - x.w);
    *(float4*)(out_zq + (size_t)n * DIM + lane * 4) = st;

    float d0 = x.x - c.x, d1 = x.y - c.y, d2 = x.z - c.z, d3 = x.w - c.w;
    float s2 = (d0 * d0 + d1 * d1) + (d2 * d2 + d3 * d3);
#pragma unroll
    for (int off = 1; off < 64; off <<= 1)
        s2 += __shfl_xor(s2, off, 64);
    if (lane == 0) {
        rowloss[n] = s2;
        out_idx[n] = (float)idx;
    }
}

// ---------------------------------------------------------------- kernel D
__global__ __launch_bounds__(256) void vq_loss(const float* __restrict__ rowloss,
                                               float* __restrict__ out_loss) {
    __shared__ double sd[256];
    double s = 0.0;
    for (int i = threadIdx.x; i < N_ROWS; i += 256) s += (double)rowloss[i];
    sd[threadIdx.x] = s;
    __syncthreads();
    for (int off = 128; off; off >>= 1) {
        if (threadIdx.x < off) sd[threadIdx.x] += sd[threadIdx.x + off];
        __syncthreads();
    }
    if (threadIdx.x == 0) {
        double mean = sd[0] / (double)((size_t)N_ROWS * DIM);
        out_loss[0] = (float)(1.25 * mean);
    }
}

// ---------------------------------------------------------------- launch
extern "C" void kernel_launch(void* const* d_in, const int* in_sizes, int n_in,
                              void* d_out, int out_size, void* d_ws, size_t ws_size,
                              hipStream_t stream) {
    const float* z_e = (const float*)d_in[0];
    const float* cb  = (const float*)d_in[1];

    float* out   = (float*)d_out;
    float* zq    = out;
    float* oidx  = out + (size_t)N_ROWS * DIM;
    float* oloss = oidx + N_ROWS;

    // ws: cnorm[8192] | xnorm[8192] | rowloss[8192] | cand_cnt[64K] | cand_idx[512K]  (~2.4 MB)
    float* cnorm    = (float*)d_ws;
    float* xnorm    = cnorm + K_CODES;
    float* rowloss  = xnorm + N_ROWS;
    int*   cand_cnt = (int*)(rowloss + N_ROWS);
    int*   cand_idx = cand_cnt + N_ROWS * SPLITK;

    vq_norms   <<<(N_ROWS + K_CODES) / 4, 256, 0, stream>>>(z_e, cb, xnorm, cnorm);
    // grid (split, mtile): same-split blocks land on one XCD (round-robin) ->
    // each XCD's 1MB codebook split stays L2-resident.
    vq_mfma    <<<dim3(SPLITK, N_ROWS / 128), 256, 0, stream>>>(z_e, cb, xnorm, cnorm, cand_cnt, cand_idx);
    vq_finalize<<<N_ROWS / 4, 256, 0, stream>>>(z_e, cb, xnorm, cnorm, cand_cnt, cand_idx, zq, oidx, rowloss);
    vq_loss    <<<1, 256, 0, stream>>>(rowloss, oloss);
}

// Round 4
// 197.696 us; speedup vs baseline: 2.9232x; 1.5509x over previous
//
#include <hip/hip_runtime.h>
#include <stdint.h>

#define N_ROWS  8192   // B*S = 4*2048
#define DIM     256
#define K_CODES 8192
#define SPLITK  8
#define KS      1024          // codes per split
#define NT      128           // codes per K-tile
#define LSLOTS  16            // per-row append slots in LDS
#define GSLOTS  12            // per-row-split survivor slots in ws
// acc-space (dot) margin: covers dist-bucket/2 (1.5e-5) + 2*bf16 dot err max
// (~4.5e-5) + dropped cnorm/2 (1.9e-6). 1e-4 leaves ~1.6x slack.
#define MARGIN_ACC 1.0e-4f

typedef unsigned long long u64;
typedef unsigned short u16;
typedef short s16x8 __attribute__((ext_vector_type(8)));   // 8 bf16 = 4 VGPR
typedef float f32x4 __attribute__((ext_vector_type(4)));

__device__ __forceinline__ u64 u64min(u64 a, u64 b) { return a < b ? a : b; }

// float -> bf16 bits, round-to-nearest-even (no NaN inputs here)
__device__ __forceinline__ u16 f2bf(float f) {
    unsigned u = __float_as_uint(f);
    u += 0x7fffu + ((u >> 16) & 1u);
    return (u16)(u >> 16);
}

// async 16B global->LDS (dest = wave-uniform base + lane*16, HW-added)
__device__ __forceinline__ void gld16(void* lds, const void* g) {
    __builtin_amdgcn_global_load_lds(
        (const __attribute__((address_space(1))) unsigned int*)g,
        (__attribute__((address_space(3))) unsigned int*)lds, 16, 0, 0);
}

// ---------------------------------------------------------------- kernel A
// Fused: bf16 conversion of z_e & cb + row norms. One wave per row.
__global__ __launch_bounds__(256) void vq_prep(const float* __restrict__ z_e,
                                               const float* __restrict__ cb,
                                               u16* __restrict__ zb,
                                               u16* __restrict__ cbb,
                                               float* __restrict__ xnorm,
                                               float* __restrict__ cnorm) {
    int wid  = (blockIdx.x * 256 + threadIdx.x) >> 6;
    int lane = threadIdx.x & 63;
    const float* src; u16* d16; float* dn;
    if (wid < N_ROWS) { src = z_e + (size_t)wid * DIM; d16 = zb + (size_t)wid * DIM; dn = xnorm + wid; }
    else              { int k = wid - N_ROWS;
                        src = cb  + (size_t)k   * DIM; d16 = cbb + (size_t)k * DIM; dn = cnorm + k; }
    float4 v = *(const float4*)(src + lane * 4);
    ushort4 h;
    h.x = f2bf(v.x); h.y = f2bf(v.y); h.z = f2bf(v.z); h.w = f2bf(v.w);
    *(ushort4*)(d16 + lane * 4) = h;
    float s = (v.x * v.x + v.y * v.y) + (v.z * v.z + v.w * v.w);
#pragma unroll
    for (int off = 1; off < 64; off <<= 1)
        s += __shfl_xor(s, off, 64);
    if (lane == 0) *dn = s;
}

// ---------------------------------------------------------------- kernel B
// bf16 MFMA dot GEMM + per-row running MAX of dot (argmin dist == argmax dot;
// xnorm constant per row, cnorm<=3.8e-6 folded into margin) + margin-append.
// Block: 128 rows x 1024 codes (one split), 4 waves 2x2. Staging via
// global_load_lds w=16; XOR source swizzle (chunk c^(row&7)) makes the
// unpadded 128B-row LDS layout conflict-free (2 lanes/bank) for ds_read_b128.
__global__ __launch_bounds__(256) void vq_mfma(const u16* __restrict__ zb,
                                               const u16* __restrict__ cbb,
                                               int* __restrict__ cand_cnt,
                                               int* __restrict__ cand_idx) {
    __shared__ u16   Xs[128 * 64];   // 16 KB: [row][8 chunks of 8 bf16], swizzled
    __shared__ u16   Cs[128 * 64];
    __shared__ float lcd[128 * LSLOTS];
    __shared__ int   lci[128 * LSLOTS];
    __shared__ int   lcnt[128];
    __shared__ float gmaxs[2][128];

    const int tid   = threadIdx.x;
    const int lane  = tid & 63;
    const int wave  = tid >> 6;
    const int wm    = wave & 1;
    const int wn    = wave >> 1;
    const int quad  = lane >> 4;
    const int l16   = lane & 15;
    const int split = blockIdx.x;
    const int n0    = blockIdx.y * 128;

    if (tid < 128) lcnt[tid] = 0;

    // staging lane constants: lane covers (row srow8 of 8-group, dest chunk schunk)
    const int srow8  = lane >> 3;
    const int schunk = lane & 7;
    const int ssw    = (schunk ^ srow8) * 8;   // swizzled source chunk offset (shorts)

    float runmax[16];
#pragma unroll
    for (int t = 0; t < 16; t++) runmax[t] = -3.0e38f;

    for (int kt = 0; kt < KS / NT; kt++) {
        const int kbase = split * KS + kt * NT;
        f32x4 acc[4][4];
#pragma unroll
        for (int i = 0; i < 4; i++)
#pragma unroll
            for (int j = 0; j < 4; j++)
#pragma unroll
                for (int e = 0; e < 4; e++) acc[i][j][e] = 0.0f;

        for (int kc = 0; kc < 4; kc++) {     // 64-dim chunks
            __syncthreads();                  // prev reads done before overwrite
#pragma unroll
            for (int t = 0; t < 4; t++) {
                int rg = wave * 4 + t;        // 8-row group, wave-uniform
                int r  = rg * 8 + srow8;
                gld16(&Xs[rg * 512], zb  + (size_t)(n0 + r)    * DIM + kc * 64 + ssw);
                gld16(&Cs[rg * 512], cbb + (size_t)(kbase + r) * DIM + kc * 64 + ssw);
            }
            __syncthreads();                  // drains vmcnt (async LDS loads)
#pragma unroll
            for (int ks = 0; ks < 2; ks++) {
                s16x8 af[4], bfr[4];
#pragma unroll
                for (int i = 0; i < 4; i++)
                    af[i] = *(const s16x8*)&Xs[(wm * 64 + i * 16 + l16) * 64 +
                                               (((ks << 2) | quad) ^ (l16 & 7)) * 8];
#pragma unroll
                for (int j = 0; j < 4; j++)
                    bfr[j] = *(const s16x8*)&Cs[(wn * 64 + j * 16 + l16) * 64 +
                                                (((ks << 2) | quad) ^ (l16 & 7)) * 8];
#pragma unroll
                for (int i = 0; i < 4; i++)
#pragma unroll
                    for (int j = 0; j < 4; j++)
                        acc[i][j] = __builtin_amdgcn_mfma_f32_16x16x32_bf16(af[i], bfr[j], acc[i][j], 0, 0, 0);
            }
        }

        // ---- epilogue: in-wave row-tile max, runmax update, margin appends
#pragma unroll
        for (int i = 0; i < 4; i++)
#pragma unroll
            for (int r = 0; r < 4; r++) {
                float m = fmaxf(fmaxf(acc[i][0][r], acc[i][1][r]),
                                fmaxf(acc[i][2][r], acc[i][3][r]));
                m = fmaxf(m, __shfl_xor(m, 1, 64));
                m = fmaxf(m, __shfl_xor(m, 2, 64));
                m = fmaxf(m, __shfl_xor(m, 4, 64));
                m = fmaxf(m, __shfl_xor(m, 8, 64));
                runmax[i * 4 + r] = fmaxf(runmax[i * 4 + r], m);
                float thr = runmax[i * 4 + r] - MARGIN_ACC;
                int rl = wm * 64 + i * 16 + quad * 4 + r;
#pragma unroll
                for (int j = 0; j < 4; j++) {
                    float d = acc[i][j][r];
                    if (d >= thr) {
                        int pos = atomicAdd(&lcnt[rl], 1);
                        if (pos < LSLOTS) {
                            lcd[rl * LSLOTS + pos] = d;
                            lci[rl * LSLOTS + pos] = kbase + wn * 64 + j * 16 + l16;
                        }
                    }
                }
            }
        // next kt's first __syncthreads orders appends vs. restaging
    }

    if (l16 == 0) {
#pragma unroll
        for (int i = 0; i < 4; i++)
#pragma unroll
            for (int r = 0; r < 4; r++)
                gmaxs[wn][wm * 64 + i * 16 + quad * 4 + r] = runmax[i * 4 + r];
    }
    __syncthreads();

    // filter appends vs final row max (winner guaranteed in the superset)
    if (tid < 128) {
        int n   = n0 + tid;
        int cnt = lcnt[tid]; if (cnt > LSLOTS) cnt = LSLOTS;
        float thrf = fmaxf(gmaxs[0][tid], gmaxs[1][tid]) - MARGIN_ACC;
        int base = (n * SPLITK + split) * GSLOTS;
        int w = 0;
        for (int s = 0; s < cnt && w < GSLOTS; s++)
            if (lcd[tid * LSLOTS + s] >= thrf)
                cand_idx[base + w++] = lci[tid * LSLOTS + s];
        cand_cnt[n * SPLITK + split] = w;
    }
}

// ---------------------------------------------------------------- kernel C
// Exact fp32 recheck (association identical to the R2/R3-passing version:
// sequential fmaf d=0..255, fmaf(-2,m,xn)+cn), lexicographic (dist,idx) min;
// then gather + z_q_st + rowloss. One wave per row.
__global__ __launch_bounds__(256) void vq_finalize(const float* __restrict__ z_e,
                                                   const float* __restrict__ cb,
                                                   const float* __restrict__ xnorm,
                                                   const float* __restrict__ cnorm,
                                                   const int* __restrict__ cand_cnt,
                                                   const int* __restrict__ cand_idx,
                                                   float* __restrict__ out_zq,
                                                   float* __restrict__ out_idx,
                                                   float* __restrict__ rowloss) {
    const int n    = blockIdx.x * 4 + (threadIdx.x >> 6);
    const int lane = threadIdx.x & 63;

    int myidx = -1;
    int t = 0;
#pragma unroll
    for (int s = 0; s < SPLITK; s++) {
        int c = cand_cnt[n * SPLITK + s];
        if (lane >= t && lane < t + c)
            myidx = cand_idx[(n * SPLITK + s) * GSLOTS + (lane - t)];
        t += c;
    }

    u64 key = ~0ULL;
    if (myidx >= 0) {
        const float* xr = z_e + (size_t)n * DIM;
        const float* cr = cb + (size_t)myidx * DIM;
        float acc = 0.0f;
#pragma unroll 8
        for (int d = 0; d < DIM; d++)
            acc = __builtin_fmaf(xr[d], cr[d], acc);
        float dist = __builtin_fmaf(-2.0f, acc, xnorm[n]) + cnorm[myidx];
        key = ((u64)__float_as_uint(dist) << 32) | (unsigned)myidx;
    }
#pragma unroll
    for (int off = 1; off < 64; off <<= 1)
        key = u64min(key, __shfl_xor(key, off, 64));

    int idx = (int)(unsigned)(key & 0xffffffffu);
    if (key == ~0ULL) idx = 0;  // unreachable safety

    float4 x = *(const float4*)(z_e + (size_t)n * DIM + lane * 4);
    float4 c = *(const float4*)(cb + (size_t)idx * DIM + lane * 4);
    float4 st;
    st.x = x.x + (c.x - x.x); st.y = x.y + (c.y - x.y);
    st.z = x.z + (c.z - x.z); st.w = x.w + (c.w - x.w);
    *(float4*)(out_zq + (size_t)n * DIM + lane * 4) = st;

    float d0 = x.x - c.x, d1 = x.y - c.y, d2 = x.z - c.z, d3 = x.w - c.w;
    float s2 = (d0 * d0 + d1 * d1) + (d2 * d2 + d3 * d3);
#pragma unroll
    for (int off = 1; off < 64; off <<= 1)
        s2 += __shfl_xor(s2, off, 64);
    if (lane == 0) {
        rowloss[n] = s2;
        out_idx[n] = (float)idx;
    }
}

// ---------------------------------------------------------------- kernel D
__global__ __launch_bounds__(256) void vq_loss(const float* __restrict__ rowloss,
                                               float* __restrict__ out_loss) {
    __shared__ double sd[256];
    double s = 0.0;
    for (int i = threadIdx.x; i < N_ROWS; i += 256) s += (double)rowloss[i];
    sd[threadIdx.x] = s;
    __syncthreads();
    for (int off = 128; off; off >>= 1) {
        if (threadIdx.x < off) sd[threadIdx.x] += sd[threadIdx.x + off];
        __syncthreads();
    }
    if (threadIdx.x == 0) {
        double mean = sd[0] / (double)((size_t)N_ROWS * DIM);
        out_loss[0] = (float)(1.25 * mean);
    }
}

// ---------------------------------------------------------------- launch
extern "C" void kernel_launch(void* const* d_in, const int* in_sizes, int n_in,
                              void* d_out, int out_size, void* d_ws, size_t ws_size,
                              hipStream_t stream) {
    const float* z_e = (const float*)d_in[0];
    const float* cb  = (const float*)d_in[1];

    float* out   = (float*)d_out;
    float* zq    = out;
    float* oidx  = out + (size_t)N_ROWS * DIM;
    float* oloss = oidx + N_ROWS;

    // ws layout (~11.9 MB):
    //   zb   bf16[8192*256]  4 MB
    //   cbb  bf16[8192*256]  4 MB
    //   xnorm/cnorm/rowloss  3*32 KB
    //   cand_cnt int[8192*8] 256 KB
    //   cand_idx int[8192*8*GSLOTS] 3 MB
    u16*   zb       = (u16*)d_ws;
    u16*   cbb      = zb + (size_t)N_ROWS * DIM;
    float* xnorm    = (float*)(cbb + (size_t)K_CODES * DIM);
    float* cnorm    = xnorm + N_ROWS;
    float* rowloss  = cnorm + K_CODES;
    int*   cand_cnt = (int*)(rowloss + N_ROWS);
    int*   cand_idx = cand_cnt + N_ROWS * SPLITK;

    vq_prep    <<<(N_ROWS + K_CODES) / 4, 256, 0, stream>>>(z_e, cb, zb, cbb, xnorm, cnorm);
    // grid (split, mtile): linear%8 == split -> each split pinned to one XCD,
    // its 0.5MB bf16 codebook split + 4MB zb stay L2-resident.
    vq_mfma    <<<dim3(SPLITK, N_ROWS / 128), 256, 0, stream>>>(zb, cbb, cand_cnt, cand_idx);
    vq_finalize<<<N_ROWS / 4, 256, 0, stream>>>(z_e, cb, xnorm, cnorm, cand_cnt, cand_idx, zq, oidx, rowloss);
    vq_loss    <<<1, 256, 0, stream>>>(rowloss, oloss);
}